// Round 12
// baseline (246.066 us; speedup 1.0000x reference)
//
#include <hip/hip_runtime.h>

typedef float f32x4 __attribute__((ext_vector_type(4)));
typedef short bf16x8 __attribute__((ext_vector_type(8)));

#define MFMA16(a, b, c) __builtin_amdgcn_mfma_f32_16x16x32_bf16((a), (b), (c), 0, 0, 0)
#define WAITV8() asm volatile("s_waitcnt vmcnt(8)" ::: "memory")
#define WAITV0() asm volatile("s_waitcnt vmcnt(0)" ::: "memory")
#define WAITL0() asm volatile("s_waitcnt lgkmcnt(0)" ::: "memory")
#define BARRIER() __builtin_amdgcn_s_barrier()
#define SCHED0() __builtin_amdgcn_sched_barrier(0)

constexpr int S_ = 2048;
constexpr int D_ = 768;
constexpr int H_ = 12;
constexpr int DH = 64;
constexpr int B_ = 2;
constexpr int M_ = B_ * S_;   // 4096 rows
constexpr int BH = B_ * H_;   // 24 (b,h) pairs

typedef unsigned short u16;
typedef unsigned int u32;

__device__ __forceinline__ u16 f2bf(float f) {  // RNE
  u32 u = __builtin_bit_cast(u32, f);
  u += 0x7fffu + ((u >> 16) & 1u);
  return (u16)(u >> 16);
}
__device__ __forceinline__ u32 pack2(float a, float b) {
  return (u32)f2bf(a) | ((u32)f2bf(b) << 16);
}
// round-half-up bf16 pack via v_perm: low16=bf16(lo), high16=bf16(hi). 3 VALU ops.
__device__ __forceinline__ u32 pack2r(float lo, float hi) {
  u32 a = __builtin_bit_cast(u32, lo) + 0x8000u;
  u32 b = __builtin_bit_cast(u32, hi) + 0x8000u;
  return __builtin_amdgcn_perm(b, a, 0x07060302u);  // bytes: [b.b3 b.b2 a.b3 a.b2]
}

// async global->LDS, 16B per lane. LDS dest = wave-uniform base + lane*16.
__device__ __forceinline__ void gload16(const void* g, void* l) {
  __builtin_amdgcn_global_load_lds((const __attribute__((address_space(1))) u32*)g,
                                   (__attribute__((address_space(3))) u32*)l, 16, 0, 0);
}

// ---------------- fused prep: hs->bf16, 4x W^T->bf16, mask canon -----------
// flat grid, branch by block range:
//   [0, 3072)           conv_bf16: one float4 per thread
//   [3072, 3072+2304)   conv_wT4: 24x24 tiles x 4 weights
//   [5376, 5384)        canon_mask
constexpr int PREP_NB_CONV = M_ * D_ / 4 / 256;           // 3072
constexpr int PREP_NB_W = (D_ / 32) * (D_ / 32) * 4;      // 2304
constexpr int PREP_NB_MASK = B_ * S_ / 512;               // 8
__global__ __launch_bounds__(256) void prep(const float* __restrict__ hs,
                                            const float* __restrict__ Wq,
                                            const float* __restrict__ Wk,
                                            const float* __restrict__ Wv,
                                            const float* __restrict__ Wo,
                                            u16* __restrict__ hsb,
                                            u16* __restrict__ wqkv,
                                            u16* __restrict__ wo,
                                            const void* __restrict__ mraw,
                                            float* __restrict__ fm,
                                            u32* __restrict__ mw) {
  __shared__ float t[32][33];
  __shared__ int isBool;
  const int bid = blockIdx.x, tid = threadIdx.x;
  if (bid < PREP_NB_CONV) {
    int i = bid * 256 + tid;
    float4 v = ((const float4*)hs)[i];
    uint2 r;
    r.x = pack2(v.x, v.y);
    r.y = pack2(v.z, v.w);
    ((uint2*)hsb)[i] = r;
  } else if (bid < PREP_NB_CONV + PREP_NB_W) {
    int zz = bid - PREP_NB_CONV;
    int z = zz / 576, r = zz % 576;
    int kx = r % 24, ny = r / 24;
    const float* w = z == 0 ? Wq : z == 1 ? Wk : z == 2 ? Wv : Wo;
    u16* wt = z == 3 ? wo : wqkv + (size_t)z * D_ * D_;
    int k0 = kx << 5, n0 = ny << 5;
    int x = tid & 31, y = tid >> 5;
#pragma unroll
    for (int j = 0; j < 4; ++j) t[y + 8 * j][x] = w[(size_t)(k0 + y + 8 * j) * D_ + n0 + x];
    __syncthreads();
#pragma unroll
    for (int j = 0; j < 4; ++j) wt[(size_t)(n0 + y + 8 * j) * D_ + k0 + x] = f2bf(t[x][y + 8 * j]);
  } else {
    if (tid == 0) isBool = 0;
    __syncthreads();
    const int* mi = (const int*)mraw;
    int v = mi[tid];  // first 1KB only: safe in both interpretations
    if (v != 0 && v != 1) atomicOr(&isBool, 1);
    __syncthreads();
    const unsigned char* mb = (const unsigned char*)mraw;
    int p = (bid - PREP_NB_CONV - PREP_NB_W) * 256 + tid;  // pair index
    int m0, m1;
    if (isBool) { m0 = mb[2 * p]; m1 = mb[2 * p + 1]; }
    else        { m0 = mi[2 * p]; m1 = mi[2 * p + 1]; }
    fm[2 * p] = (float)m0;
    fm[2 * p + 1] = (float)m1;
    mw[p] = (m0 ? 0xFFFFu : 0u) | (m1 ? 0xFFFF0000u : 0u);
  }
}

// ---------------- 128x128 GEMM, BK=64, counted-vmcnt 2-barrier schedule ----
// MODE 0: fused QKV (N=2304): p=0 -> Q head-layout (*qscale), p=1 -> K head-
//         layout, p=2 -> sigma-permuted V^T. MODE 1: fp32 flat out (N=768).
template <int MODE>
__global__ __launch_bounds__(256, 2) void gemm128(const u16* __restrict__ A,
                                                  const u16* __restrict__ Wt,
                                                  const float* __restrict__ bq,
                                                  const float* __restrict__ bk,
                                                  const float* __restrict__ bv,
                                                  u16* __restrict__ oq,
                                                  u16* __restrict__ ok,
                                                  u16* __restrict__ ov,
                                                  float* __restrict__ of,
                                                  float qscale) {
  constexpr int NT = D_ / 64;  // 12
  __shared__ __align__(16) u16 lA[2][128 * 64];
  __shared__ __align__(16) u16 lB[2][128 * 64];
  const int tid = threadIdx.x, w = tid >> 6, lane = tid & 63;
  const int g = lane >> 4, c = lane & 15;
  const int m0 = blockIdx.x * 128, n0 = blockIdx.y * 128;
  const int wr = w >> 1, wc = w & 1;
  const int srow = lane >> 3, scb = ((lane & 7) * 16) ^ (srow << 4);
  const int sw = (c & 7) << 4;
  const char* Ab = (const char*)A + (size_t)m0 * (D_ * 2);
  const char* Bb = (const char*)Wt + (size_t)n0 * (D_ * 2);

  auto stage = [&](int buf, int t) {
    int k0b = t * 128;
#pragma unroll
    for (int a = 0; a < 4; ++a) {
      int rr = w * 32 + a * 8;
      gload16(Ab + (size_t)(rr + srow) * (D_ * 2) + k0b + scb, &lA[buf][rr * 64]);
      gload16(Bb + (size_t)(rr + srow) * (D_ * 2) + k0b + scb, &lB[buf][rr * 64]);
    }
  };

  f32x4 acc[4][4] = {};
  auto compute = [&](int buf) {
    const char* pa = (const char*)&lA[buf][0];
    const char* pb = (const char*)&lB[buf][0];
#pragma unroll
    for (int kk = 0; kk < 2; ++kk) {
      const int cs = (kk * 64 + g * 16) ^ sw;
      bf16x8 af[4], bf[4];
#pragma unroll
      for (int i = 0; i < 4; ++i)
        af[i] = *(const bf16x8*)(pa + (wr * 64 + i * 16 + c) * 128 + cs);
#pragma unroll
      for (int j = 0; j < 4; ++j)
        bf[j] = *(const bf16x8*)(pb + (wc * 64 + j * 16 + c) * 128 + cs);
      __builtin_amdgcn_s_setprio(1);
#pragma unroll
      for (int i = 0; i < 4; ++i)
#pragma unroll
        for (int j = 0; j < 4; ++j) acc[i][j] = MFMA16(af[i], bf[j], acc[i][j]);
      __builtin_amdgcn_s_setprio(0);
    }
  };

  stage(0, 0);
  int buf = 0;
#pragma unroll 1
  for (int t = 0; t < NT; ++t) {
    if (t + 1 < NT) { stage(buf ^ 1, t + 1); WAITV8(); }
    else            { WAITV0(); }
    BARRIER(); SCHED0();
    compute(buf);
    SCHED0(); WAITL0(); BARRIER();
    buf ^= 1;
  }

  if (MODE == 0) {
    const int p = n0 / D_;  // tile never crosses a projection (768 % 128 == 0)
    const int nn0 = n0 - p * D_;
    const float* bias = p == 0 ? bq : p == 1 ? bk : bv;
    const float sc = p == 0 ? qscale : 1.0f;
#pragma unroll
    for (int j = 0; j < 4; ++j) {
      int nn = nn0 + wc * 64 + j * 16 + c;
      float bvv = bias[nn];
      int h = nn >> 6, d = nn & 63;
#pragma unroll
      for (int i = 0; i < 4; ++i) {
        int m = m0 + wr * 64 + i * 16 + g * 4;
        int b = m >> 11, s = m & (S_ - 1);
        if (p < 2) {
          u16* dst = (p == 0 ? oq : ok) + ((size_t)(b * H_ + h) * S_ + s) * DH + d;
#pragma unroll
          for (int r = 0; r < 4; ++r) dst[(size_t)r * DH] = f2bf((acc[i][j][r] + bvv) * sc);
        } else {
          // sigma: within each 32-key chunk, slots 8q+0..3 <- keys 4q..,
          // slots 8q+4..7 <- keys 16+4q..
          int chunk = s >> 5, kq = (s >> 2) & 7;
          int sb = kq < 4 ? 8 * kq : 8 * (kq - 4) + 4;
          uint2 pk;
          pk.x = pack2r(acc[i][j][0] + bvv, acc[i][j][1] + bvv);
          pk.y = pack2r(acc[i][j][2] + bvv, acc[i][j][3] + bvv);
          *(uint2*)(ov + ((size_t)((b * H_ + h) * DH + d)) * S_ + chunk * 32 + sb) = pk;
        }
      }
    }
  } else {
#pragma unroll
    for (int j = 0; j < 4; ++j) {
      int n = n0 + wc * 64 + j * 16 + c;
      float bvv = bq[n];
#pragma unroll
      for (int i = 0; i < 4; ++i) {
        int m = m0 + wr * 64 + i * 16 + g * 4;
#pragma unroll
        for (int r = 0; r < 4; ++r) of[(size_t)(m + r) * D_ + n] = acc[i][j][r] + bvv;
      }
    }
  }
}

// ---------------- dual-softmax flash attention (round-7 structure) ---------
// grid 768 (1D, XCD-chunk-swizzled), block 256 = 4 waves in a 2x2 grid:
// wave w -> q-half qh=w&1 (32 q, dual Q-frags), key-half kh=w>>1 (32 keys).
// K[64x64]+Vt[64x64] LDS tiles (XOR-swizzled, double-buffered), proven
// stage->compute->syncthreads loop. Mask words read DIRECT from global
// (L2-hit) -> LDS = exactly 32 KB -> 4 blocks/CU (16 waves) with
// launch_bounds(256,4) (VGPR cap 128; our ~90 fits, no spill — the (256,5)
// trap caps at 64 VGPR and spills, round 10). End reduce reuses the staging
// LDS in two phases. Q pre-scaled by log2(e)/8 -> exp2 scores.
__global__ __launch_bounds__(256, 4) void attn(const u16* __restrict__ Q,
                                               const u16* __restrict__ K,
                                               const u16* __restrict__ Vt,
                                               const float* __restrict__ fm,
                                               const u32* __restrict__ mw,
                                               u16* __restrict__ ctx) {
  constexpr int NT = S_ / 64;
  __shared__ __align__(16) char smem[32768];
  char* lKb = smem;            // 2 x 8192
  char* lVb = smem + 16384;    // 2 x 8192

  const int tid = threadIdx.x;
  const int w = tid >> 6, lane = tid & 63;
  const int g = lane >> 4, c = lane & 15;
  const int qh = w & 1, kh = w >> 1;
  const int bid = blockIdx.x;
  const int wg = (bid & 7) * 96 + (bid >> 3);  // bijective XCD-chunk swizzle
  const int qt = wg & 31, bh = wg >> 5;
  const int b = bh / H_, h = bh % H_;
  const int qbase = qt * 64 + qh * 32;

  const u16* Qp = Q + ((size_t)bh * S_ + qbase) * DH;
  const char* Kp = (const char*)(K + (size_t)bh * S_ * DH);
  const char* Vp = (const char*)(Vt + (size_t)bh * DH * S_);
  const float* fmp = fm + b * S_;
  const char* mwp = (const char*)(mw + b * (S_ / 2)) + kh * 64 + g * 8;

  bf16x8 qf[2][2];
#pragma unroll
  for (int qs = 0; qs < 2; ++qs)
#pragma unroll
    for (int kk = 0; kk < 2; ++kk)
      qf[qs][kk] = *(const bf16x8*)(Qp + (qs * 16 + c) * DH + kk * 32 + g * 8);

  u32 ow = (c == 0) ? 0x3F803F80u : 0u;
  uint4 owv = {ow, ow, ow, ow};
  bf16x8 onesf = __builtin_bit_cast(bf16x8, owv);

  const int srow = lane >> 3;
  const int scb = ((lane & 7) * 16) ^ (srow << 4);
  const int sw = (c & 7) << 4;
  const int r8a = w * 2, r8b = w * 2 + 1;
  const int rowA = r8a * 8 + srow, rowB = r8b * 8 + srow;

  f32x4 accf[2][4] = {}, accb[2][4] = {}, alf[2] = {}, alb[2] = {};

  auto stage = [&](int buf, int t) {
    const char* kb_ = Kp + (size_t)t * 8192;
    const char* vb_ = Vp + (size_t)t * 128;
    gload16(kb_ + (size_t)rowA * 128 + scb, lKb + buf * 8192 + r8a * 1024);
    gload16(kb_ + (size_t)rowB * 128 + scb, lKb + buf * 8192 + r8b * 1024);
    gload16(vb_ + (size_t)rowA * 4096 + scb, lVb + buf * 8192 + r8a * 1024);
    gload16(vb_ + (size_t)rowB * 4096 + scb, lVb + buf * 8192 + r8b * 1024);
  };

  auto compute = [&](int buf, int t) {
    const char* kt = lKb + buf * 8192;
    const char* vtl = lVb + buf * 8192;
    const int kc = kh;  // this wave's key-half
    uint2 m01 = *(const uint2*)(mwp + (size_t)t * 128);        // direct global (L2)
    uint2 m23 = *(const uint2*)(mwp + (size_t)t * 128 + 32);
    bf16x8 k00 = *(const bf16x8*)(kt + (kc * 32 + c) * 128 + ((g * 16) ^ sw));
    bf16x8 k01 = *(const bf16x8*)(kt + (kc * 32 + c) * 128 + ((64 + g * 16) ^ sw));
    bf16x8 k10 = *(const bf16x8*)(kt + (kc * 32 + 16 + c) * 128 + ((g * 16) ^ sw));
    bf16x8 k11 = *(const bf16x8*)(kt + (kc * 32 + 16 + c) * 128 + ((64 + g * 16) ^ sw));
    const int csel = (kc * 64 + g * 16) ^ sw;
    bf16x8 vf0 = *(const bf16x8*)(vtl + (0 * 16 + c) * 128 + csel);
    bf16x8 vf1 = *(const bf16x8*)(vtl + (1 * 16 + c) * 128 + csel);
    bf16x8 vf2 = *(const bf16x8*)(vtl + (2 * 16 + c) * 128 + csel);
    bf16x8 vf3 = *(const bf16x8*)(vtl + (3 * 16 + c) * 128 + csel);
#pragma unroll
    for (int qs = 0; qs < 2; ++qs) {
      f32x4 st0 = {}, st1 = {};
      __builtin_amdgcn_s_setprio(1);
      st0 = MFMA16(k00, qf[qs][0], st0);
      st0 = MFMA16(k01, qf[qs][1], st0);
      st1 = MFMA16(k10, qf[qs][0], st1);
      st1 = MFMA16(k11, qf[qs][1], st1);
      __builtin_amdgcn_s_setprio(0);
      u32 ew0 = pack2r(__builtin_amdgcn_exp2f(st0[0]), __builtin_amdgcn_exp2f(st0[1]));
      u32 ew1 = pack2r(__builtin_amdgcn_exp2f(st0[2]), __builtin_amdgcn_exp2f(st0[3]));
      u32 ew2 = pack2r(__builtin_amdgcn_exp2f(st1[0]), __builtin_amdgcn_exp2f(st1[1]));
      u32 ew3 = pack2r(__builtin_amdgcn_exp2f(st1[2]), __builtin_amdgcn_exp2f(st1[3]));
      u32 pf0 = ew0 & m01.x, pf1 = ew1 & m01.y;
      u32 pf2 = ew2 & m23.x, pf3 = ew3 & m23.y;
      uint4 pfv = {pf0, pf1, pf2, pf3};
      uint4 pbv = {ew0 ^ pf0, ew1 ^ pf1, ew2 ^ pf2, ew3 ^ pf3};
      bf16x8 paf = __builtin_bit_cast(bf16x8, pfv);
      bf16x8 pab = __builtin_bit_cast(bf16x8, pbv);
      __builtin_amdgcn_s_setprio(1);
      accf[qs][0] = MFMA16(paf, vf0, accf[qs][0]);
      accb[qs][0] = MFMA16(pab, vf0, accb[qs][0]);
      accf[qs][1] = MFMA16(paf, vf1, accf[qs][1]);
      accb[qs][1] = MFMA16(pab, vf1, accb[qs][1]);
      accf[qs][2] = MFMA16(paf, vf2, accf[qs][2]);
      accb[qs][2] = MFMA16(pab, vf2, accb[qs][2]);
      accf[qs][3] = MFMA16(paf, vf3, accf[qs][3]);
      accb[qs][3] = MFMA16(pab, vf3, accb[qs][3]);
      alf[qs] = MFMA16(paf, onesf, alf[qs]);
      alb[qs] = MFMA16(pab, onesf, alb[qs]);
      __builtin_amdgcn_s_setprio(0);
    }
  };

  stage(0, 0);
  __syncthreads();

  int buf = 0;
#pragma unroll 1
  for (int t = 0; t < NT; ++t) {
    if (t + 1 < NT) stage(buf ^ 1, t + 1);
    compute(buf, t);
    __syncthreads();
    buf ^= 1;
  }

  // ---- two-phase cross-wave key-half reduction (sums are additive) ----
  // 20480 B region reused by both q-halves; overlays the staging LDS.
  f32x4* red = (f32x4*)smem;
#pragma unroll 1
  for (int ph = 0; ph < 2; ++ph) {
    if (qh == ph && kh == 1) {
#pragma unroll
      for (int qs = 0; qs < 2; ++qs)
#pragma unroll
        for (int n = 0; n < 4; ++n) {
          red[(qs * 4 + n) * 64 + lane] = accf[qs][n];
          red[(8 + qs * 4 + n) * 64 + lane] = accb[qs][n];
        }
      red[16 * 64 + lane] = alf[0];
      red[17 * 64 + lane] = alf[1];
      red[18 * 64 + lane] = alb[0];
      red[19 * 64 + lane] = alb[1];
    }
    __syncthreads();
    if (qh == ph && kh == 0) {
#pragma unroll
      for (int qs = 0; qs < 2; ++qs)
#pragma unroll
        for (int n = 0; n < 4; ++n) {
          accf[qs][n] += red[(qs * 4 + n) * 64 + lane];
          accb[qs][n] += red[(8 + qs * 4 + n) * 64 + lane];
        }
      alf[0] += red[16 * 64 + lane];
      alf[1] += red[17 * 64 + lane];
      alb[0] += red[18 * 64 + lane];
      alb[1] += red[19 * 64 + lane];
    }
    __syncthreads();
  }

  if (kh == 0) {
#pragma unroll
    for (int qs = 0; qs < 2; ++qs) {
      const int qw = qbase + qs * 16;
#pragma unroll
      for (int r = 0; r < 4; ++r) {
        int ql = g * 4 + r;
        float lfr = __shfl(alf[qs][r], g * 16);  // D[row=4g+r][col=0] in lane 16g
        float lbr = __shfl(alb[qs][r], g * 16);
        bool fg = fmp[qw + ql] > 0.5f;
        float inv_f = (lfr > 0.f) ? 1.f / lfr : 0.f;
        float inv_b = (lbr > 0.f) ? 1.f / lbr : 0.f;
        float inv_all = 1.f / (lfr + lbr);
#pragma unroll
        for (int n = 0; n < 4; ++n) {
          float o = fg ? (accf[qs][n][r] * inv_f + accb[qs][n][r] * inv_b)
                       : ((accf[qs][n][r] + accb[qs][n][r]) * inv_all);
          ctx[((size_t)(b * S_ + qw + ql)) * D_ + h * DH + n * 16 + c] = f2bf(o);
        }
      }
    }
  }
}

// ---------------- launch ---------------------------------------------------
extern "C" void kernel_launch(void* const* d_in, const int* in_sizes, int n_in,
                              void* d_out, int out_size, void* d_ws, size_t ws_size,
                              hipStream_t stream) {
  const float* hs = (const float*)d_in[0];
  const float* Wq = (const float*)d_in[1];
  const float* bq = (const float*)d_in[2];
  const float* Wk = (const float*)d_in[3];
  const float* bk = (const float*)d_in[4];
  const float* Wv = (const float*)d_in[5];
  const float* bv = (const float*)d_in[6];
  const float* Wo = (const float*)d_in[7];
  const float* bo = (const float*)d_in[8];
  const void* mraw = d_in[9];

  char* ws = (char*)d_ws;
  size_t off = 0;
  auto alloc = [&](size_t bytes) {
    void* p = ws + off;
    off += (bytes + 255) & ~(size_t)255;
    return p;
  };
  u16* hsb = (u16*)alloc((size_t)M_ * D_ * 2);
  u16* wqkvT = (u16*)alloc((size_t)3 * D_ * D_ * 2);
  u16* woT = (u16*)alloc((size_t)D_ * D_ * 2);
  u16* qb = (u16*)alloc((size_t)M_ * D_ * 2);
  u16* kb = (u16*)alloc((size_t)M_ * D_ * 2);
  u16* vtb = (u16*)alloc((size_t)M_ * D_ * 2);
  u16* ctx = (u16*)alloc((size_t)M_ * D_ * 2);
  float* fmf = (float*)alloc((size_t)B_ * S_ * 4);
  u32* mwb = (u32*)alloc((size_t)B_ * S_ / 2 * 4);

  prep<<<PREP_NB_CONV + PREP_NB_W + PREP_NB_MASK, 256, 0, stream>>>(
      hs, Wq, Wk, Wv, Wo, hsb, wqkvT, woT, mraw, fmf, mwb);

  const float qscale = 0.125f * 1.44269504088896f;  // 1/sqrt(Dh) * log2(e)
  gemm128<0><<<dim3(M_ / 128, 3 * D_ / 128), 256, 0, stream>>>(
      hsb, wqkvT, bq, bk, bv, qb, kb, vtb, nullptr, qscale);

  attn<<<dim3(768), 256, 0, stream>>>(qb, kb, vtb, fmf, mwb, ctx);

  gemm128<1><<<dim3(M_ / 128, D_ / 128), 256, 0, stream>>>(
      ctx, woT, bo, nullptr, nullptr, nullptr, nullptr, nullptr, (float*)d_out, 1.0f);
}

// Round 13
// 103.027 us; speedup vs baseline: 2.3884x; 2.3884x over previous
//
#include <hip/hip_runtime.h>

typedef float f32x4 __attribute__((ext_vector_type(4)));
typedef short bf16x8 __attribute__((ext_vector_type(8)));

#define MFMA16(a, b, c) __builtin_amdgcn_mfma_f32_16x16x32_bf16((a), (b), (c), 0, 0, 0)
#define WAITV8() asm volatile("s_waitcnt vmcnt(8)" ::: "memory")
#define WAITV0() asm volatile("s_waitcnt vmcnt(0)" ::: "memory")
#define WAITL0() asm volatile("s_waitcnt lgkmcnt(0)" ::: "memory")
#define BARRIER() __builtin_amdgcn_s_barrier()
#define SCHED0() __builtin_amdgcn_sched_barrier(0)

constexpr int S_ = 2048;
constexpr int D_ = 768;
constexpr int H_ = 12;
constexpr int DH = 64;
constexpr int B_ = 2;
constexpr int M_ = B_ * S_;   // 4096 rows
constexpr int BH = B_ * H_;   // 24 (b,h) pairs

typedef unsigned short u16;
typedef unsigned int u32;

__device__ __forceinline__ u16 f2bf(float f) {  // RNE
  u32 u = __builtin_bit_cast(u32, f);
  u += 0x7fffu + ((u >> 16) & 1u);
  return (u16)(u >> 16);
}
__device__ __forceinline__ u32 pack2(float a, float b) {
  return (u32)f2bf(a) | ((u32)f2bf(b) << 16);
}
// round-half-up bf16 pack via v_perm: low16=bf16(lo), high16=bf16(hi). 3 VALU ops.
__device__ __forceinline__ u32 pack2r(float lo, float hi) {
  u32 a = __builtin_bit_cast(u32, lo) + 0x8000u;
  u32 b = __builtin_bit_cast(u32, hi) + 0x8000u;
  return __builtin_amdgcn_perm(b, a, 0x07060302u);  // bytes: [b.b3 b.b2 a.b3 a.b2]
}

// async global->LDS, 16B per lane. LDS dest = wave-uniform base + lane*16.
__device__ __forceinline__ void gload16(const void* g, void* l) {
  __builtin_amdgcn_global_load_lds((const __attribute__((address_space(1))) u32*)g,
                                   (__attribute__((address_space(3))) u32*)l, 16, 0, 0);
}

// ---------------- fused prep: hs->bf16, 4x W^T->bf16, mask canon -----------
// flat grid, branch by block range:
//   [0, 3072)           conv_bf16: one float4 per thread
//   [3072, 3072+2304)   conv_wT4: 24x24 tiles x 4 weights
//   [5376, 5384)        canon_mask
constexpr int PREP_NB_CONV = M_ * D_ / 4 / 256;           // 3072
constexpr int PREP_NB_W = (D_ / 32) * (D_ / 32) * 4;      // 2304
constexpr int PREP_NB_MASK = B_ * S_ / 512;               // 8
__global__ __launch_bounds__(256) void prep(const float* __restrict__ hs,
                                            const float* __restrict__ Wq,
                                            const float* __restrict__ Wk,
                                            const float* __restrict__ Wv,
                                            const float* __restrict__ Wo,
                                            u16* __restrict__ hsb,
                                            u16* __restrict__ wqkv,
                                            u16* __restrict__ wo,
                                            const void* __restrict__ mraw,
                                            float* __restrict__ fm,
                                            u32* __restrict__ mw) {
  __shared__ float t[32][33];
  __shared__ int isBool;
  const int bid = blockIdx.x, tid = threadIdx.x;
  if (bid < PREP_NB_CONV) {
    int i = bid * 256 + tid;
    float4 v = ((const float4*)hs)[i];
    uint2 r;
    r.x = pack2(v.x, v.y);
    r.y = pack2(v.z, v.w);
    ((uint2*)hsb)[i] = r;
  } else if (bid < PREP_NB_CONV + PREP_NB_W) {
    int zz = bid - PREP_NB_CONV;
    int z = zz / 576, r = zz % 576;
    int kx = r % 24, ny = r / 24;
    const float* w = z == 0 ? Wq : z == 1 ? Wk : z == 2 ? Wv : Wo;
    u16* wt = z == 3 ? wo : wqkv + (size_t)z * D_ * D_;
    int k0 = kx << 5, n0 = ny << 5;
    int x = tid & 31, y = tid >> 5;
#pragma unroll
    for (int j = 0; j < 4; ++j) t[y + 8 * j][x] = w[(size_t)(k0 + y + 8 * j) * D_ + n0 + x];
    __syncthreads();
#pragma unroll
    for (int j = 0; j < 4; ++j) wt[(size_t)(n0 + y + 8 * j) * D_ + k0 + x] = f2bf(t[x][y + 8 * j]);
  } else {
    if (tid == 0) isBool = 0;
    __syncthreads();
    const int* mi = (const int*)mraw;
    int v = mi[tid];  // first 1KB only: safe in both interpretations
    if (v != 0 && v != 1) atomicOr(&isBool, 1);
    __syncthreads();
    const unsigned char* mb = (const unsigned char*)mraw;
    int p = (bid - PREP_NB_CONV - PREP_NB_W) * 256 + tid;  // pair index
    int m0, m1;
    if (isBool) { m0 = mb[2 * p]; m1 = mb[2 * p + 1]; }
    else        { m0 = mi[2 * p]; m1 = mi[2 * p + 1]; }
    fm[2 * p] = (float)m0;
    fm[2 * p + 1] = (float)m1;
    mw[p] = (m0 ? 0xFFFFu : 0u) | (m1 ? 0xFFFF0000u : 0u);
  }
}

// ---------------- 128x128 GEMM, BK=64, counted-vmcnt 2-barrier schedule ----
// MODE 0: fused QKV (N=2304): p=0 -> Q head-layout (*qscale), p=1 -> K head-
//         layout, p=2 -> sigma-permuted V^T. MODE 1: fp32 flat out (N=768).
template <int MODE>
__global__ __launch_bounds__(256, 2) void gemm128(const u16* __restrict__ A,
                                                  const u16* __restrict__ Wt,
                                                  const float* __restrict__ bq,
                                                  const float* __restrict__ bk,
                                                  const float* __restrict__ bv,
                                                  u16* __restrict__ oq,
                                                  u16* __restrict__ ok,
                                                  u16* __restrict__ ov,
                                                  float* __restrict__ of,
                                                  float qscale) {
  constexpr int NT = D_ / 64;  // 12
  __shared__ __align__(16) u16 lA[2][128 * 64];
  __shared__ __align__(16) u16 lB[2][128 * 64];
  const int tid = threadIdx.x, w = tid >> 6, lane = tid & 63;
  const int g = lane >> 4, c = lane & 15;
  const int m0 = blockIdx.x * 128, n0 = blockIdx.y * 128;
  const int wr = w >> 1, wc = w & 1;
  const int srow = lane >> 3, scb = ((lane & 7) * 16) ^ (srow << 4);
  const int sw = (c & 7) << 4;
  const char* Ab = (const char*)A + (size_t)m0 * (D_ * 2);
  const char* Bb = (const char*)Wt + (size_t)n0 * (D_ * 2);

  auto stage = [&](int buf, int t) {
    int k0b = t * 128;
#pragma unroll
    for (int a = 0; a < 4; ++a) {
      int rr = w * 32 + a * 8;
      gload16(Ab + (size_t)(rr + srow) * (D_ * 2) + k0b + scb, &lA[buf][rr * 64]);
      gload16(Bb + (size_t)(rr + srow) * (D_ * 2) + k0b + scb, &lB[buf][rr * 64]);
    }
  };

  f32x4 acc[4][4] = {};
  auto compute = [&](int buf) {
    const char* pa = (const char*)&lA[buf][0];
    const char* pb = (const char*)&lB[buf][0];
#pragma unroll
    for (int kk = 0; kk < 2; ++kk) {
      const int cs = (kk * 64 + g * 16) ^ sw;
      bf16x8 af[4], bf[4];
#pragma unroll
      for (int i = 0; i < 4; ++i)
        af[i] = *(const bf16x8*)(pa + (wr * 64 + i * 16 + c) * 128 + cs);
#pragma unroll
      for (int j = 0; j < 4; ++j)
        bf[j] = *(const bf16x8*)(pb + (wc * 64 + j * 16 + c) * 128 + cs);
      __builtin_amdgcn_s_setprio(1);
#pragma unroll
      for (int i = 0; i < 4; ++i)
#pragma unroll
        for (int j = 0; j < 4; ++j) acc[i][j] = MFMA16(af[i], bf[j], acc[i][j]);
      __builtin_amdgcn_s_setprio(0);
    }
  };

  stage(0, 0);
  int buf = 0;
#pragma unroll 1
  for (int t = 0; t < NT; ++t) {
    if (t + 1 < NT) { stage(buf ^ 1, t + 1); WAITV8(); }
    else            { WAITV0(); }
    BARRIER(); SCHED0();
    compute(buf);
    SCHED0(); WAITL0(); BARRIER();
    buf ^= 1;
  }

  if (MODE == 0) {
    const int p = n0 / D_;  // tile never crosses a projection (768 % 128 == 0)
    const int nn0 = n0 - p * D_;
    const float* bias = p == 0 ? bq : p == 1 ? bk : bv;
    const float sc = p == 0 ? qscale : 1.0f;
#pragma unroll
    for (int j = 0; j < 4; ++j) {
      int nn = nn0 + wc * 64 + j * 16 + c;
      float bvv = bias[nn];
      int h = nn >> 6, d = nn & 63;
#pragma unroll
      for (int i = 0; i < 4; ++i) {
        int m = m0 + wr * 64 + i * 16 + g * 4;
        int b = m >> 11, s = m & (S_ - 1);
        if (p < 2) {
          u16* dst = (p == 0 ? oq : ok) + ((size_t)(b * H_ + h) * S_ + s) * DH + d;
#pragma unroll
          for (int r = 0; r < 4; ++r) dst[(size_t)r * DH] = f2bf((acc[i][j][r] + bvv) * sc);
        } else {
          // sigma: within each 32-key chunk, slots 8q+0..3 <- keys 4q..,
          // slots 8q+4..7 <- keys 16+4q..
          int chunk = s >> 5, kq = (s >> 2) & 7;
          int sb = kq < 4 ? 8 * kq : 8 * (kq - 4) + 4;
          uint2 pk;
          pk.x = pack2r(acc[i][j][0] + bvv, acc[i][j][1] + bvv);
          pk.y = pack2r(acc[i][j][2] + bvv, acc[i][j][3] + bvv);
          *(uint2*)(ov + ((size_t)((b * H_ + h) * DH + d)) * S_ + chunk * 32 + sb) = pk;
        }
      }
    }
  } else {
#pragma unroll
    for (int j = 0; j < 4; ++j) {
      int n = n0 + wc * 64 + j * 16 + c;
      float bvv = bq[n];
#pragma unroll
      for (int i = 0; i < 4; ++i) {
        int m = m0 + wr * 64 + i * 16 + g * 4;
#pragma unroll
        for (int r = 0; r < 4; ++r) of[(size_t)(m + r) * D_ + n] = acc[i][j][r] + bvv;
      }
    }
  }
}

// ---------------- dual-softmax flash attention (round-7 structure) ---------
// grid 768 (1D, XCD-chunk-swizzled), block 256 = 4 waves in a 2x2 grid:
// wave w -> q-half qh=w&1 (32 q, dual Q-frags), key-half kh=w>>1 (32 keys).
// K[64x64]+Vt[64x64] LDS tiles (XOR-swizzled, double-buffered), proven
// stage->compute->syncthreads loop. Mask words read DIRECT from global
// (L2-hit) -> LDS = 32 KB (5 blocks/CU by LDS). launch_bounds(256,3):
// VGPR quantum 84+ fits, NO SPILL. (256,4) forces the 64-VGPR quantum and
// spills all accumulators (round 12: 326 MB scratch, 200 us) — never raise.
// End reduce reuses staging LDS in two phases. Q pre-scaled by log2(e)/8.
__global__ __launch_bounds__(256, 3) void attn(const u16* __restrict__ Q,
                                               const u16* __restrict__ K,
                                               const u16* __restrict__ Vt,
                                               const float* __restrict__ fm,
                                               const u32* __restrict__ mw,
                                               u16* __restrict__ ctx) {
  constexpr int NT = S_ / 64;
  __shared__ __align__(16) char smem[32768];
  char* lKb = smem;            // 2 x 8192
  char* lVb = smem + 16384;    // 2 x 8192

  const int tid = threadIdx.x;
  const int w = tid >> 6, lane = tid & 63;
  const int g = lane >> 4, c = lane & 15;
  const int qh = w & 1, kh = w >> 1;
  const int bid = blockIdx.x;
  const int wg = (bid & 7) * 96 + (bid >> 3);  // bijective XCD-chunk swizzle
  const int qt = wg & 31, bh = wg >> 5;
  const int b = bh / H_, h = bh % H_;
  const int qbase = qt * 64 + qh * 32;

  const u16* Qp = Q + ((size_t)bh * S_ + qbase) * DH;
  const char* Kp = (const char*)(K + (size_t)bh * S_ * DH);
  const char* Vp = (const char*)(Vt + (size_t)bh * DH * S_);
  const float* fmp = fm + b * S_;
  const char* mwp = (const char*)(mw + b * (S_ / 2)) + kh * 64 + g * 8;

  bf16x8 qf[2][2];
#pragma unroll
  for (int qs = 0; qs < 2; ++qs)
#pragma unroll
    for (int kk = 0; kk < 2; ++kk)
      qf[qs][kk] = *(const bf16x8*)(Qp + (qs * 16 + c) * DH + kk * 32 + g * 8);

  u32 ow = (c == 0) ? 0x3F803F80u : 0u;
  uint4 owv = {ow, ow, ow, ow};
  bf16x8 onesf = __builtin_bit_cast(bf16x8, owv);

  const int srow = lane >> 3;
  const int scb = ((lane & 7) * 16) ^ (srow << 4);
  const int sw = (c & 7) << 4;
  const int r8a = w * 2, r8b = w * 2 + 1;
  const int rowA = r8a * 8 + srow, rowB = r8b * 8 + srow;

  f32x4 accf[2][4] = {}, accb[2][4] = {}, alf[2] = {}, alb[2] = {};

  auto stage = [&](int buf, int t) {
    const char* kb_ = Kp + (size_t)t * 8192;
    const char* vb_ = Vp + (size_t)t * 128;
    gload16(kb_ + (size_t)rowA * 128 + scb, lKb + buf * 8192 + r8a * 1024);
    gload16(kb_ + (size_t)rowB * 128 + scb, lKb + buf * 8192 + r8b * 1024);
    gload16(vb_ + (size_t)rowA * 4096 + scb, lVb + buf * 8192 + r8a * 1024);
    gload16(vb_ + (size_t)rowB * 4096 + scb, lVb + buf * 8192 + r8b * 1024);
  };

  auto compute = [&](int buf, int t) {
    const char* kt = lKb + buf * 8192;
    const char* vtl = lVb + buf * 8192;
    const int kc = kh;  // this wave's key-half
    uint2 m01 = *(const uint2*)(mwp + (size_t)t * 128);        // direct global (L2)
    uint2 m23 = *(const uint2*)(mwp + (size_t)t * 128 + 32);
    bf16x8 k00 = *(const bf16x8*)(kt + (kc * 32 + c) * 128 + ((g * 16) ^ sw));
    bf16x8 k01 = *(const bf16x8*)(kt + (kc * 32 + c) * 128 + ((64 + g * 16) ^ sw));
    bf16x8 k10 = *(const bf16x8*)(kt + (kc * 32 + 16 + c) * 128 + ((g * 16) ^ sw));
    bf16x8 k11 = *(const bf16x8*)(kt + (kc * 32 + 16 + c) * 128 + ((64 + g * 16) ^ sw));
    const int csel = (kc * 64 + g * 16) ^ sw;
    bf16x8 vf0 = *(const bf16x8*)(vtl + (0 * 16 + c) * 128 + csel);
    bf16x8 vf1 = *(const bf16x8*)(vtl + (1 * 16 + c) * 128 + csel);
    bf16x8 vf2 = *(const bf16x8*)(vtl + (2 * 16 + c) * 128 + csel);
    bf16x8 vf3 = *(const bf16x8*)(vtl + (3 * 16 + c) * 128 + csel);
#pragma unroll
    for (int qs = 0; qs < 2; ++qs) {
      f32x4 st0 = {}, st1 = {};
      __builtin_amdgcn_s_setprio(1);
      st0 = MFMA16(k00, qf[qs][0], st0);
      st0 = MFMA16(k01, qf[qs][1], st0);
      st1 = MFMA16(k10, qf[qs][0], st1);
      st1 = MFMA16(k11, qf[qs][1], st1);
      __builtin_amdgcn_s_setprio(0);
      u32 ew0 = pack2r(__builtin_amdgcn_exp2f(st0[0]), __builtin_amdgcn_exp2f(st0[1]));
      u32 ew1 = pack2r(__builtin_amdgcn_exp2f(st0[2]), __builtin_amdgcn_exp2f(st0[3]));
      u32 ew2 = pack2r(__builtin_amdgcn_exp2f(st1[0]), __builtin_amdgcn_exp2f(st1[1]));
      u32 ew3 = pack2r(__builtin_amdgcn_exp2f(st1[2]), __builtin_amdgcn_exp2f(st1[3]));
      u32 pf0 = ew0 & m01.x, pf1 = ew1 & m01.y;
      u32 pf2 = ew2 & m23.x, pf3 = ew3 & m23.y;
      uint4 pfv = {pf0, pf1, pf2, pf3};
      uint4 pbv = {ew0 ^ pf0, ew1 ^ pf1, ew2 ^ pf2, ew3 ^ pf3};
      bf16x8 paf = __builtin_bit_cast(bf16x8, pfv);
      bf16x8 pab = __builtin_bit_cast(bf16x8, pbv);
      __builtin_amdgcn_s_setprio(1);
      accf[qs][0] = MFMA16(paf, vf0, accf[qs][0]);
      accb[qs][0] = MFMA16(pab, vf0, accb[qs][0]);
      accf[qs][1] = MFMA16(paf, vf1, accf[qs][1]);
      accb[qs][1] = MFMA16(pab, vf1, accb[qs][1]);
      accf[qs][2] = MFMA16(paf, vf2, accf[qs][2]);
      accb[qs][2] = MFMA16(pab, vf2, accb[qs][2]);
      accf[qs][3] = MFMA16(paf, vf3, accf[qs][3]);
      accb[qs][3] = MFMA16(pab, vf3, accb[qs][3]);
      alf[qs] = MFMA16(paf, onesf, alf[qs]);
      alb[qs] = MFMA16(pab, onesf, alb[qs]);
      __builtin_amdgcn_s_setprio(0);
    }
  };

  stage(0, 0);
  __syncthreads();

  int buf = 0;
#pragma unroll 1
  for (int t = 0; t < NT; ++t) {
    if (t + 1 < NT) stage(buf ^ 1, t + 1);
    compute(buf, t);
    __syncthreads();
    buf ^= 1;
  }

  // ---- two-phase cross-wave key-half reduction (sums are additive) ----
  // 20480 B region reused by both q-halves; overlays the staging LDS.
  f32x4* red = (f32x4*)smem;
#pragma unroll 1
  for (int ph = 0; ph < 2; ++ph) {
    if (qh == ph && kh == 1) {
#pragma unroll
      for (int qs = 0; qs < 2; ++qs)
#pragma unroll
        for (int n = 0; n < 4; ++n) {
          red[(qs * 4 + n) * 64 + lane] = accf[qs][n];
          red[(8 + qs * 4 + n) * 64 + lane] = accb[qs][n];
        }
      red[16 * 64 + lane] = alf[0];
      red[17 * 64 + lane] = alf[1];
      red[18 * 64 + lane] = alb[0];
      red[19 * 64 + lane] = alb[1];
    }
    __syncthreads();
    if (qh == ph && kh == 0) {
#pragma unroll
      for (int qs = 0; qs < 2; ++qs)
#pragma unroll
        for (int n = 0; n < 4; ++n) {
          accf[qs][n] += red[(qs * 4 + n) * 64 + lane];
          accb[qs][n] += red[(8 + qs * 4 + n) * 64 + lane];
        }
      alf[0] += red[16 * 64 + lane];
      alf[1] += red[17 * 64 + lane];
      alb[0] += red[18 * 64 + lane];
      alb[1] += red[19 * 64 + lane];
    }
    __syncthreads();
  }

  if (kh == 0) {
#pragma unroll
    for (int qs = 0; qs < 2; ++qs) {
      const int qw = qbase + qs * 16;
#pragma unroll
      for (int r = 0; r < 4; ++r) {
        int ql = g * 4 + r;
        float lfr = __shfl(alf[qs][r], g * 16);  // D[row=4g+r][col=0] in lane 16g
        float lbr = __shfl(alb[qs][r], g * 16);
        bool fg = fmp[qw + ql] > 0.5f;
        float inv_f = (lfr > 0.f) ? 1.f / lfr : 0.f;
        float inv_b = (lbr > 0.f) ? 1.f / lbr : 0.f;
        float inv_all = 1.f / (lfr + lbr);
#pragma unroll
        for (int n = 0; n < 4; ++n) {
          float o = fg ? (accf[qs][n][r] * inv_f + accb[qs][n][r] * inv_b)
                       : ((accf[qs][n][r] + accb[qs][n][r]) * inv_all);
          ctx[((size_t)(b * S_ + qw + ql)) * D_ + h * DH + n * 16 + c] = f2bf(o);
        }
      }
    }
  }
}

// ---------------- launch ---------------------------------------------------
extern "C" void kernel_launch(void* const* d_in, const int* in_sizes, int n_in,
                              void* d_out, int out_size, void* d_ws, size_t ws_size,
                              hipStream_t stream) {
  const float* hs = (const float*)d_in[0];
  const float* Wq = (const float*)d_in[1];
  const float* bq = (const float*)d_in[2];
  const float* Wk = (const float*)d_in[3];
  const float* bk = (const float*)d_in[4];
  const float* Wv = (const float*)d_in[5];
  const float* bv = (const float*)d_in[6];
  const float* Wo = (const float*)d_in[7];
  const float* bo = (const float*)d_in[8];
  const void* mraw = d_in[9];

  char* ws = (char*)d_ws;
  size_t off = 0;
  auto alloc = [&](size_t bytes) {
    void* p = ws + off;
    off += (bytes + 255) & ~(size_t)255;
    return p;
  };
  u16* hsb = (u16*)alloc((size_t)M_ * D_ * 2);
  u16* wqkvT = (u16*)alloc((size_t)3 * D_ * D_ * 2);
  u16* woT = (u16*)alloc((size_t)D_ * D_ * 2);
  u16* qb = (u16*)alloc((size_t)M_ * D_ * 2);
  u16* kb = (u16*)alloc((size_t)M_ * D_ * 2);
  u16* vtb = (u16*)alloc((size_t)M_ * D_ * 2);
  u16* ctx = (u16*)alloc((size_t)M_ * D_ * 2);
  float* fmf = (float*)alloc((size_t)B_ * S_ * 4);
  u32* mwb = (u32*)alloc((size_t)B_ * S_ / 2 * 4);

  prep<<<PREP_NB_CONV + PREP_NB_W + PREP_NB_MASK, 256, 0, stream>>>(
      hs, Wq, Wk, Wv, Wo, hsb, wqkvT, woT, mraw, fmf, mwb);

  const float qscale = 0.125f * 1.44269504088896f;  // 1/sqrt(Dh) * log2(e)
  gemm128<0><<<dim3(M_ / 128, 3 * D_ / 128), 256, 0, stream>>>(
      hsb, wqkvT, bq, bk, bv, qb, kb, vtb, nullptr, qscale);

  attn<<<dim3(768), 256, 0, stream>>>(qb, kb, vtb, fmf, mwb, ctx);

  gemm128<1><<<dim3(M_ / 128, D_ / 128), 256, 0, stream>>>(
      ctx, woT, bo, nullptr, nullptr, nullptr, nullptr, nullptr, (float*)d_out, 1.0f);
}

// Round 14
// 99.781 us; speedup vs baseline: 2.4661x; 1.0325x over previous
//
#include <hip/hip_runtime.h>

typedef float f32x4 __attribute__((ext_vector_type(4)));
typedef short bf16x8 __attribute__((ext_vector_type(8)));

#define MFMA16(a, b, c) __builtin_amdgcn_mfma_f32_16x16x32_bf16((a), (b), (c), 0, 0, 0)
#define WAITV8() asm volatile("s_waitcnt vmcnt(8)" ::: "memory")
#define WAITV0() asm volatile("s_waitcnt vmcnt(0)" ::: "memory")
#define WAITL0() asm volatile("s_waitcnt lgkmcnt(0)" ::: "memory")
#define BARRIER() __builtin_amdgcn_s_barrier()
#define SCHED0() __builtin_amdgcn_sched_barrier(0)

constexpr int S_ = 2048;
constexpr int D_ = 768;
constexpr int H_ = 12;
constexpr int DH = 64;
constexpr int B_ = 2;
constexpr int M_ = B_ * S_;   // 4096 rows
constexpr int BH = B_ * H_;   // 24 (b,h) pairs

typedef unsigned short u16;
typedef unsigned int u32;

__device__ __forceinline__ u16 f2bf(float f) {  // RNE
  u32 u = __builtin_bit_cast(u32, f);
  u += 0x7fffu + ((u >> 16) & 1u);
  return (u16)(u >> 16);
}
__device__ __forceinline__ u32 pack2(float a, float b) {
  return (u32)f2bf(a) | ((u32)f2bf(b) << 16);
}
// round-half-up bf16 pack via v_perm: low16=bf16(lo), high16=bf16(hi). 3 VALU ops.
__device__ __forceinline__ u32 pack2r(float lo, float hi) {
  u32 a = __builtin_bit_cast(u32, lo) + 0x8000u;
  u32 b = __builtin_bit_cast(u32, hi) + 0x8000u;
  return __builtin_amdgcn_perm(b, a, 0x07060302u);  // bytes: [b.b3 b.b2 a.b3 a.b2]
}

// async global->LDS, 16B per lane. LDS dest = wave-uniform base + lane*16.
__device__ __forceinline__ void gload16(const void* g, void* l) {
  __builtin_amdgcn_global_load_lds((const __attribute__((address_space(1))) u32*)g,
                                   (__attribute__((address_space(3))) u32*)l, 16, 0, 0);
}

// ---------------- fused prep: hs->bf16, 4x W^T->bf16, mask canon -----------
// flat grid, branch by block range:
//   [0, 3072)           conv_bf16: one float4 per thread
//   [3072, 3072+2304)   conv_wT4: 24x24 tiles x 4 weights
//   [5376, 5384)        canon_mask
constexpr int PREP_NB_CONV = M_ * D_ / 4 / 256;           // 3072
constexpr int PREP_NB_W = (D_ / 32) * (D_ / 32) * 4;      // 2304
constexpr int PREP_NB_MASK = B_ * S_ / 512;               // 8
__global__ __launch_bounds__(256) void prep(const float* __restrict__ hs,
                                            const float* __restrict__ Wq,
                                            const float* __restrict__ Wk,
                                            const float* __restrict__ Wv,
                                            const float* __restrict__ Wo,
                                            u16* __restrict__ hsb,
                                            u16* __restrict__ wqkv,
                                            u16* __restrict__ wo,
                                            const void* __restrict__ mraw,
                                            float* __restrict__ fm,
                                            u32* __restrict__ mw) {
  __shared__ float t[32][33];
  __shared__ int isBool;
  const int bid = blockIdx.x, tid = threadIdx.x;
  if (bid < PREP_NB_CONV) {
    int i = bid * 256 + tid;
    float4 v = ((const float4*)hs)[i];
    uint2 r;
    r.x = pack2(v.x, v.y);
    r.y = pack2(v.z, v.w);
    ((uint2*)hsb)[i] = r;
  } else if (bid < PREP_NB_CONV + PREP_NB_W) {
    int zz = bid - PREP_NB_CONV;
    int z = zz / 576, r = zz % 576;
    int kx = r % 24, ny = r / 24;
    const float* w = z == 0 ? Wq : z == 1 ? Wk : z == 2 ? Wv : Wo;
    u16* wt = z == 3 ? wo : wqkv + (size_t)z * D_ * D_;
    int k0 = kx << 5, n0 = ny << 5;
    int x = tid & 31, y = tid >> 5;
#pragma unroll
    for (int j = 0; j < 4; ++j) t[y + 8 * j][x] = w[(size_t)(k0 + y + 8 * j) * D_ + n0 + x];
    __syncthreads();
#pragma unroll
    for (int j = 0; j < 4; ++j) wt[(size_t)(n0 + y + 8 * j) * D_ + k0 + x] = f2bf(t[x][y + 8 * j]);
  } else {
    if (tid == 0) isBool = 0;
    __syncthreads();
    const int* mi = (const int*)mraw;
    int v = mi[tid];  // first 1KB only: safe in both interpretations
    if (v != 0 && v != 1) atomicOr(&isBool, 1);
    __syncthreads();
    const unsigned char* mb = (const unsigned char*)mraw;
    int p = (bid - PREP_NB_CONV - PREP_NB_W) * 256 + tid;  // pair index
    int m0, m1;
    if (isBool) { m0 = mb[2 * p]; m1 = mb[2 * p + 1]; }
    else        { m0 = mi[2 * p]; m1 = mi[2 * p + 1]; }
    fm[2 * p] = (float)m0;
    fm[2 * p + 1] = (float)m1;
    mw[p] = (m0 ? 0xFFFFu : 0u) | (m1 ? 0xFFFF0000u : 0u);
  }
}

// ---------------- 128x128 GEMM, BK=64, counted-vmcnt 2-barrier schedule ----
// MODE 0: fused QKV (N=2304): p=0 -> Q head-layout (*qscale), p=1 -> K head-
//         layout, p=2 -> sigma-permuted V^T. MODE 1: fp32 flat out (N=768).
template <int MODE>
__global__ __launch_bounds__(256, 2) void gemm128(const u16* __restrict__ A,
                                                  const u16* __restrict__ Wt,
                                                  const float* __restrict__ bq,
                                                  const float* __restrict__ bk,
                                                  const float* __restrict__ bv,
                                                  u16* __restrict__ oq,
                                                  u16* __restrict__ ok,
                                                  u16* __restrict__ ov,
                                                  float* __restrict__ of,
                                                  float qscale) {
  constexpr int NT = D_ / 64;  // 12
  __shared__ __align__(16) u16 lA[2][128 * 64];
  __shared__ __align__(16) u16 lB[2][128 * 64];
  const int tid = threadIdx.x, w = tid >> 6, lane = tid & 63;
  const int g = lane >> 4, c = lane & 15;
  const int m0 = blockIdx.x * 128, n0 = blockIdx.y * 128;
  const int wr = w >> 1, wc = w & 1;
  const int srow = lane >> 3, scb = ((lane & 7) * 16) ^ (srow << 4);
  const int sw = (c & 7) << 4;
  const char* Ab = (const char*)A + (size_t)m0 * (D_ * 2);
  const char* Bb = (const char*)Wt + (size_t)n0 * (D_ * 2);

  auto stage = [&](int buf, int t) {
    int k0b = t * 128;
#pragma unroll
    for (int a = 0; a < 4; ++a) {
      int rr = w * 32 + a * 8;
      gload16(Ab + (size_t)(rr + srow) * (D_ * 2) + k0b + scb, &lA[buf][rr * 64]);
      gload16(Bb + (size_t)(rr + srow) * (D_ * 2) + k0b + scb, &lB[buf][rr * 64]);
    }
  };

  f32x4 acc[4][4] = {};
  auto compute = [&](int buf) {
    const char* pa = (const char*)&lA[buf][0];
    const char* pb = (const char*)&lB[buf][0];
#pragma unroll
    for (int kk = 0; kk < 2; ++kk) {
      const int cs = (kk * 64 + g * 16) ^ sw;
      bf16x8 af[4], bf[4];
#pragma unroll
      for (int i = 0; i < 4; ++i)
        af[i] = *(const bf16x8*)(pa + (wr * 64 + i * 16 + c) * 128 + cs);
#pragma unroll
      for (int j = 0; j < 4; ++j)
        bf[j] = *(const bf16x8*)(pb + (wc * 64 + j * 16 + c) * 128 + cs);
      __builtin_amdgcn_s_setprio(1);
#pragma unroll
      for (int i = 0; i < 4; ++i)
#pragma unroll
        for (int j = 0; j < 4; ++j) acc[i][j] = MFMA16(af[i], bf[j], acc[i][j]);
      __builtin_amdgcn_s_setprio(0);
    }
  };

  stage(0, 0);
  int buf = 0;
#pragma unroll 1
  for (int t = 0; t < NT; ++t) {
    if (t + 1 < NT) { stage(buf ^ 1, t + 1); WAITV8(); }
    else            { WAITV0(); }
    BARRIER(); SCHED0();
    compute(buf);
    SCHED0(); WAITL0(); BARRIER();
    buf ^= 1;
  }

  if (MODE == 0) {
    const int p = n0 / D_;  // tile never crosses a projection (768 % 128 == 0)
    const int nn0 = n0 - p * D_;
    const float* bias = p == 0 ? bq : p == 1 ? bk : bv;
    const float sc = p == 0 ? qscale : 1.0f;
#pragma unroll
    for (int j = 0; j < 4; ++j) {
      int nn = nn0 + wc * 64 + j * 16 + c;
      float bvv = bias[nn];
      int h = nn >> 6, d = nn & 63;
#pragma unroll
      for (int i = 0; i < 4; ++i) {
        int m = m0 + wr * 64 + i * 16 + g * 4;
        int b = m >> 11, s = m & (S_ - 1);
        if (p < 2) {
          u16* dst = (p == 0 ? oq : ok) + ((size_t)(b * H_ + h) * S_ + s) * DH + d;
#pragma unroll
          for (int r = 0; r < 4; ++r) dst[(size_t)r * DH] = f2bf((acc[i][j][r] + bvv) * sc);
        } else {
          // sigma: within each 32-key chunk, slots 8q+0..3 <- keys 4q..,
          // slots 8q+4..7 <- keys 16+4q..
          int chunk = s >> 5, kq = (s >> 2) & 7;
          int sb = kq < 4 ? 8 * kq : 8 * (kq - 4) + 4;
          uint2 pk;
          pk.x = pack2r(acc[i][j][0] + bvv, acc[i][j][1] + bvv);
          pk.y = pack2r(acc[i][j][2] + bvv, acc[i][j][3] + bvv);
          *(uint2*)(ov + ((size_t)((b * H_ + h) * DH + d)) * S_ + chunk * 32 + sb) = pk;
        }
      }
    }
  } else {
#pragma unroll
    for (int j = 0; j < 4; ++j) {
      int n = n0 + wc * 64 + j * 16 + c;
      float bvv = bq[n];
#pragma unroll
      for (int i = 0; i < 4; ++i) {
        int m = m0 + wr * 64 + i * 16 + g * 4;
#pragma unroll
        for (int r = 0; r < 4; ++r) of[(size_t)(m + r) * D_ + n] = acc[i][j][r] + bvv;
      }
    }
  }
}

// ---------------- dual-softmax flash attention (round-7 structure) ---------
// grid 768 (1D, XCD-chunk-swizzled), block 256 = 4 waves in a 2x2 grid:
// wave w -> q-half qh=w&1 (32 q, dual Q-frags), key-half kh=w>>1 (32 keys).
// K[64x64]+Vt[64x64] LDS tiles (XOR-swizzled, double-buffered), proven
// stage->compute->syncthreads loop. Mask words STAGED IN LDS (one gload16
// per wave covers the whole batch; direct-global variant cost +5us, r13).
// launch_bounds(256,3): VGPR 84, no spill. NEVER raise the min-waves arg:
// (256,4)->64-VGPR quantum->full spill (r12); (256,5) same (r10).
// End reduce reuses staging LDS in two phases. Q pre-scaled by log2(e)/8.
__global__ __launch_bounds__(256, 3) void attn(const u16* __restrict__ Q,
                                               const u16* __restrict__ K,
                                               const u16* __restrict__ Vt,
                                               const float* __restrict__ fm,
                                               const u32* __restrict__ mw,
                                               u16* __restrict__ ctx) {
  constexpr int NT = S_ / 64;
  // [0,16K) K dbuf, [16K,32K) V dbuf, [32K,36K) mask words; reduce overlays.
  __shared__ __align__(16) char smem[36864];
  char* lKb = smem;            // 2 x 8192
  char* lVb = smem + 16384;    // 2 x 8192
  char* lMb = smem + 32768;    // 4096

  const int tid = threadIdx.x;
  const int w = tid >> 6, lane = tid & 63;
  const int g = lane >> 4, c = lane & 15;
  const int qh = w & 1, kh = w >> 1;
  const int bid = blockIdx.x;
  const int wg = (bid & 7) * 96 + (bid >> 3);  // bijective XCD-chunk swizzle
  const int qt = wg & 31, bh = wg >> 5;
  const int b = bh / H_, h = bh % H_;
  const int qbase = qt * 64 + qh * 32;

  const u16* Qp = Q + ((size_t)bh * S_ + qbase) * DH;
  const char* Kp = (const char*)(K + (size_t)bh * S_ * DH);
  const char* Vp = (const char*)(Vt + (size_t)bh * DH * S_);
  const float* fmp = fm + b * S_;
  const char* mwp = (const char*)(mw + b * (S_ / 2));

  bf16x8 qf[2][2];
#pragma unroll
  for (int qs = 0; qs < 2; ++qs)
#pragma unroll
    for (int kk = 0; kk < 2; ++kk)
      qf[qs][kk] = *(const bf16x8*)(Qp + (qs * 16 + c) * DH + kk * 32 + g * 8);

  u32 ow = (c == 0) ? 0x3F803F80u : 0u;
  uint4 owv = {ow, ow, ow, ow};
  bf16x8 onesf = __builtin_bit_cast(bf16x8, owv);

  const int srow = lane >> 3;
  const int scb = ((lane & 7) * 16) ^ (srow << 4);
  const int sw = (c & 7) << 4;
  const int r8a = w * 2, r8b = w * 2 + 1;
  const int rowA = r8a * 8 + srow, rowB = r8b * 8 + srow;

  f32x4 accf[2][4] = {}, accb[2][4] = {}, alf[2] = {}, alb[2] = {};

  auto stage = [&](int buf, int t) {
    const char* kb_ = Kp + (size_t)t * 8192;
    const char* vb_ = Vp + (size_t)t * 128;
    gload16(kb_ + (size_t)rowA * 128 + scb, lKb + buf * 8192 + r8a * 1024);
    gload16(kb_ + (size_t)rowB * 128 + scb, lKb + buf * 8192 + r8b * 1024);
    gload16(vb_ + (size_t)rowA * 4096 + scb, lVb + buf * 8192 + r8a * 1024);
    gload16(vb_ + (size_t)rowB * 4096 + scb, lVb + buf * 8192 + r8b * 1024);
  };

  auto compute = [&](int buf, int t) {
    const char* kt = lKb + buf * 8192;
    const char* vtl = lVb + buf * 8192;
    const int kc = kh;  // this wave's key-half
    uint2 m01 = *(const uint2*)(lMb + t * 128 + kc * 64 + g * 8);
    uint2 m23 = *(const uint2*)(lMb + t * 128 + kc * 64 + 32 + g * 8);
    bf16x8 k00 = *(const bf16x8*)(kt + (kc * 32 + c) * 128 + ((g * 16) ^ sw));
    bf16x8 k01 = *(const bf16x8*)(kt + (kc * 32 + c) * 128 + ((64 + g * 16) ^ sw));
    bf16x8 k10 = *(const bf16x8*)(kt + (kc * 32 + 16 + c) * 128 + ((g * 16) ^ sw));
    bf16x8 k11 = *(const bf16x8*)(kt + (kc * 32 + 16 + c) * 128 + ((64 + g * 16) ^ sw));
    const int csel = (kc * 64 + g * 16) ^ sw;
    bf16x8 vf0 = *(const bf16x8*)(vtl + (0 * 16 + c) * 128 + csel);
    bf16x8 vf1 = *(const bf16x8*)(vtl + (1 * 16 + c) * 128 + csel);
    bf16x8 vf2 = *(const bf16x8*)(vtl + (2 * 16 + c) * 128 + csel);
    bf16x8 vf3 = *(const bf16x8*)(vtl + (3 * 16 + c) * 128 + csel);
#pragma unroll
    for (int qs = 0; qs < 2; ++qs) {
      f32x4 st0 = {}, st1 = {};
      __builtin_amdgcn_s_setprio(1);
      st0 = MFMA16(k00, qf[qs][0], st0);
      st0 = MFMA16(k01, qf[qs][1], st0);
      st1 = MFMA16(k10, qf[qs][0], st1);
      st1 = MFMA16(k11, qf[qs][1], st1);
      __builtin_amdgcn_s_setprio(0);
      u32 ew0 = pack2r(__builtin_amdgcn_exp2f(st0[0]), __builtin_amdgcn_exp2f(st0[1]));
      u32 ew1 = pack2r(__builtin_amdgcn_exp2f(st0[2]), __builtin_amdgcn_exp2f(st0[3]));
      u32 ew2 = pack2r(__builtin_amdgcn_exp2f(st1[0]), __builtin_amdgcn_exp2f(st1[1]));
      u32 ew3 = pack2r(__builtin_amdgcn_exp2f(st1[2]), __builtin_amdgcn_exp2f(st1[3]));
      u32 pf0 = ew0 & m01.x, pf1 = ew1 & m01.y;
      u32 pf2 = ew2 & m23.x, pf3 = ew3 & m23.y;
      uint4 pfv = {pf0, pf1, pf2, pf3};
      uint4 pbv = {ew0 ^ pf0, ew1 ^ pf1, ew2 ^ pf2, ew3 ^ pf3};
      bf16x8 paf = __builtin_bit_cast(bf16x8, pfv);
      bf16x8 pab = __builtin_bit_cast(bf16x8, pbv);
      __builtin_amdgcn_s_setprio(1);
      accf[qs][0] = MFMA16(paf, vf0, accf[qs][0]);
      accb[qs][0] = MFMA16(pab, vf0, accb[qs][0]);
      accf[qs][1] = MFMA16(paf, vf1, accf[qs][1]);
      accb[qs][1] = MFMA16(pab, vf1, accb[qs][1]);
      accf[qs][2] = MFMA16(paf, vf2, accf[qs][2]);
      accb[qs][2] = MFMA16(pab, vf2, accb[qs][2]);
      accf[qs][3] = MFMA16(paf, vf3, accf[qs][3]);
      accb[qs][3] = MFMA16(pab, vf3, accb[qs][3]);
      alf[qs] = MFMA16(paf, onesf, alf[qs]);
      alb[qs] = MFMA16(pab, onesf, alb[qs]);
      __builtin_amdgcn_s_setprio(0);
    }
  };

  // prologue: mask words (1 gload16/wave = 4 KB total) + tile 0, one drain
  gload16(mwp + w * 1024 + lane * 16, lMb + w * 1024);
  stage(0, 0);
  __syncthreads();

  int buf = 0;
#pragma unroll 1
  for (int t = 0; t < NT; ++t) {
    if (t + 1 < NT) stage(buf ^ 1, t + 1);
    compute(buf, t);
    __syncthreads();
    buf ^= 1;
  }

  // ---- two-phase cross-wave key-half reduction (sums are additive) ----
  // 20480 B region reused by both q-halves; overlays the staging LDS.
  f32x4* red = (f32x4*)smem;
#pragma unroll 1
  for (int ph = 0; ph < 2; ++ph) {
    if (qh == ph && kh == 1) {
#pragma unroll
      for (int qs = 0; qs < 2; ++qs)
#pragma unroll
        for (int n = 0; n < 4; ++n) {
          red[(qs * 4 + n) * 64 + lane] = accf[qs][n];
          red[(8 + qs * 4 + n) * 64 + lane] = accb[qs][n];
        }
      red[16 * 64 + lane] = alf[0];
      red[17 * 64 + lane] = alf[1];
      red[18 * 64 + lane] = alb[0];
      red[19 * 64 + lane] = alb[1];
    }
    __syncthreads();
    if (qh == ph && kh == 0) {
#pragma unroll
      for (int qs = 0; qs < 2; ++qs)
#pragma unroll
        for (int n = 0; n < 4; ++n) {
          accf[qs][n] += red[(qs * 4 + n) * 64 + lane];
          accb[qs][n] += red[(8 + qs * 4 + n) * 64 + lane];
        }
      alf[0] += red[16 * 64 + lane];
      alf[1] += red[17 * 64 + lane];
      alb[0] += red[18 * 64 + lane];
      alb[1] += red[19 * 64 + lane];
    }
    __syncthreads();
  }

  if (kh == 0) {
#pragma unroll
    for (int qs = 0; qs < 2; ++qs) {
      const int qw = qbase + qs * 16;
#pragma unroll
      for (int r = 0; r < 4; ++r) {
        int ql = g * 4 + r;
        float lfr = __shfl(alf[qs][r], g * 16);  // D[row=4g+r][col=0] in lane 16g
        float lbr = __shfl(alb[qs][r], g * 16);
        bool fg = fmp[qw + ql] > 0.5f;
        float inv_f = (lfr > 0.f) ? 1.f / lfr : 0.f;
        float inv_b = (lbr > 0.f) ? 1.f / lbr : 0.f;
        float inv_all = 1.f / (lfr + lbr);
#pragma unroll
        for (int n = 0; n < 4; ++n) {
          float o = fg ? (accf[qs][n][r] * inv_f + accb[qs][n][r] * inv_b)
                       : ((accf[qs][n][r] + accb[qs][n][r]) * inv_all);
          ctx[((size_t)(b * S_ + qw + ql)) * D_ + h * DH + n * 16 + c] = f2bf(o);
        }
      }
    }
  }
}

// ---------------- launch ---------------------------------------------------
extern "C" void kernel_launch(void* const* d_in, const int* in_sizes, int n_in,
                              void* d_out, int out_size, void* d_ws, size_t ws_size,
                              hipStream_t stream) {
  const float* hs = (const float*)d_in[0];
  const float* Wq = (const float*)d_in[1];
  const float* bq = (const float*)d_in[2];
  const float* Wk = (const float*)d_in[3];
  const float* bk = (const float*)d_in[4];
  const float* Wv = (const float*)d_in[5];
  const float* bv = (const float*)d_in[6];
  const float* Wo = (const float*)d_in[7];
  const float* bo = (const float*)d_in[8];
  const void* mraw = d_in[9];

  char* ws = (char*)d_ws;
  size_t off = 0;
  auto alloc = [&](size_t bytes) {
    void* p = ws + off;
    off += (bytes + 255) & ~(size_t)255;
    return p;
  };
  u16* hsb = (u16*)alloc((size_t)M_ * D_ * 2);
  u16* wqkvT = (u16*)alloc((size_t)3 * D_ * D_ * 2);
  u16* woT = (u16*)alloc((size_t)D_ * D_ * 2);
  u16* qb = (u16*)alloc((size_t)M_ * D_ * 2);
  u16* kb = (u16*)alloc((size_t)M_ * D_ * 2);
  u16* vtb = (u16*)alloc((size_t)M_ * D_ * 2);
  u16* ctx = (u16*)alloc((size_t)M_ * D_ * 2);
  float* fmf = (float*)alloc((size_t)B_ * S_ * 4);
  u32* mwb = (u32*)alloc((size_t)B_ * S_ / 2 * 4);

  prep<<<PREP_NB_CONV + PREP_NB_W + PREP_NB_MASK, 256, 0, stream>>>(
      hs, Wq, Wk, Wv, Wo, hsb, wqkvT, woT, mraw, fmf, mwb);

  const float qscale = 0.125f * 1.44269504088896f;  // 1/sqrt(Dh) * log2(e)
  gemm128<0><<<dim3(M_ / 128, 3 * D_ / 128), 256, 0, stream>>>(
      hsb, wqkvT, bq, bk, bv, qb, kb, vtb, nullptr, qscale);

  attn<<<dim3(768), 256, 0, stream>>>(qb, kb, vtb, fmf, mwb, ctx);

  gemm128<1><<<dim3(M_ / 128, D_ / 128), 256, 0, stream>>>(
      ctx, woT, bo, nullptr, nullptr, nullptr, nullptr, nullptr, (float*)d_out, 1.0f);
}

// Round 15
// 97.128 us; speedup vs baseline: 2.5334x; 1.0273x over previous
//
#include <hip/hip_runtime.h>

typedef float f32x4 __attribute__((ext_vector_type(4)));
typedef short bf16x8 __attribute__((ext_vector_type(8)));

#define MFMA16(a, b, c) __builtin_amdgcn_mfma_f32_16x16x32_bf16((a), (b), (c), 0, 0, 0)
#define WAITV8() asm volatile("s_waitcnt vmcnt(8)" ::: "memory")
#define WAITV0() asm volatile("s_waitcnt vmcnt(0)" ::: "memory")
#define WAITL0() asm volatile("s_waitcnt lgkmcnt(0)" ::: "memory")
#define BARRIER() __builtin_amdgcn_s_barrier()
#define SCHED0() __builtin_amdgcn_sched_barrier(0)

constexpr int S_ = 2048;
constexpr int D_ = 768;
constexpr int H_ = 12;
constexpr int DH = 64;
constexpr int B_ = 2;
constexpr int M_ = B_ * S_;   // 4096 rows
constexpr int BH = B_ * H_;   // 24 (b,h) pairs

typedef unsigned short u16;
typedef unsigned int u32;

__device__ __forceinline__ u16 f2bf(float f) {  // RNE
  u32 u = __builtin_bit_cast(u32, f);
  u += 0x7fffu + ((u >> 16) & 1u);
  return (u16)(u >> 16);
}
__device__ __forceinline__ u32 pack2(float a, float b) {
  return (u32)f2bf(a) | ((u32)f2bf(b) << 16);
}
// round-half-up bf16 pack via v_perm: low16=bf16(lo), high16=bf16(hi). 3 VALU ops.
__device__ __forceinline__ u32 pack2r(float lo, float hi) {
  u32 a = __builtin_bit_cast(u32, lo) + 0x8000u;
  u32 b = __builtin_bit_cast(u32, hi) + 0x8000u;
  return __builtin_amdgcn_perm(b, a, 0x07060302u);  // bytes: [b.b3 b.b2 a.b3 a.b2]
}
// packed f32x2 -> bf16x2 in ONE VALU op (RNE). T12 recipe (m214v22).
__device__ __forceinline__ u32 cvtpk(float lo, float hi) {
  u32 r;
  asm("v_cvt_pk_bf16_f32 %0, %1, %2" : "=v"(r) : "v"(lo), "v"(hi));
  return r;
}

// async global->LDS, 16B per lane. LDS dest = wave-uniform base + lane*16.
__device__ __forceinline__ void gload16(const void* g, void* l) {
  __builtin_amdgcn_global_load_lds((const __attribute__((address_space(1))) u32*)g,
                                   (__attribute__((address_space(3))) u32*)l, 16, 0, 0);
}

// ---------------- fused prep: hs->bf16, 4x W^T->bf16, mask canon -----------
// flat grid, branch by block range:
//   [0, 3072)           conv_bf16: one float4 per thread
//   [3072, 3072+2304)   conv_wT4: 24x24 tiles x 4 weights
//   [5376, 5384)        canon_mask
constexpr int PREP_NB_CONV = M_ * D_ / 4 / 256;           // 3072
constexpr int PREP_NB_W = (D_ / 32) * (D_ / 32) * 4;      // 2304
constexpr int PREP_NB_MASK = B_ * S_ / 512;               // 8
__global__ __launch_bounds__(256) void prep(const float* __restrict__ hs,
                                            const float* __restrict__ Wq,
                                            const float* __restrict__ Wk,
                                            const float* __restrict__ Wv,
                                            const float* __restrict__ Wo,
                                            u16* __restrict__ hsb,
                                            u16* __restrict__ wqkv,
                                            u16* __restrict__ wo,
                                            const void* __restrict__ mraw,
                                            float* __restrict__ fm,
                                            u32* __restrict__ mw) {
  __shared__ float t[32][33];
  __shared__ int isBool;
  const int bid = blockIdx.x, tid = threadIdx.x;
  if (bid < PREP_NB_CONV) {
    int i = bid * 256 + tid;
    float4 v = ((const float4*)hs)[i];
    uint2 r;
    r.x = pack2(v.x, v.y);
    r.y = pack2(v.z, v.w);
    ((uint2*)hsb)[i] = r;
  } else if (bid < PREP_NB_CONV + PREP_NB_W) {
    int zz = bid - PREP_NB_CONV;
    int z = zz / 576, r = zz % 576;
    int kx = r % 24, ny = r / 24;
    const float* w = z == 0 ? Wq : z == 1 ? Wk : z == 2 ? Wv : Wo;
    u16* wt = z == 3 ? wo : wqkv + (size_t)z * D_ * D_;
    int k0 = kx << 5, n0 = ny << 5;
    int x = tid & 31, y = tid >> 5;
#pragma unroll
    for (int j = 0; j < 4; ++j) t[y + 8 * j][x] = w[(size_t)(k0 + y + 8 * j) * D_ + n0 + x];
    __syncthreads();
#pragma unroll
    for (int j = 0; j < 4; ++j) wt[(size_t)(n0 + y + 8 * j) * D_ + k0 + x] = f2bf(t[x][y + 8 * j]);
  } else {
    if (tid == 0) isBool = 0;
    __syncthreads();
    const int* mi = (const int*)mraw;
    int v = mi[tid];  // first 1KB only: safe in both interpretations
    if (v != 0 && v != 1) atomicOr(&isBool, 1);
    __syncthreads();
    const unsigned char* mb = (const unsigned char*)mraw;
    int p = (bid - PREP_NB_CONV - PREP_NB_W) * 256 + tid;  // pair index
    int m0, m1;
    if (isBool) { m0 = mb[2 * p]; m1 = mb[2 * p + 1]; }
    else        { m0 = mi[2 * p]; m1 = mi[2 * p + 1]; }
    fm[2 * p] = (float)m0;
    fm[2 * p + 1] = (float)m1;
    mw[p] = (m0 ? 0xFFFFu : 0u) | (m1 ? 0xFFFF0000u : 0u);
  }
}

// ---------------- 128x128 GEMM, BK=64, counted-vmcnt 2-barrier schedule ----
// MODE 0: fused QKV (N=2304): p=0 -> Q head-layout (*qscale), p=1 -> K head-
//         layout, p=2 -> sigma-permuted V^T. MODE 1: fp32 flat out (N=768).
template <int MODE>
__global__ __launch_bounds__(256, 2) void gemm128(const u16* __restrict__ A,
                                                  const u16* __restrict__ Wt,
                                                  const float* __restrict__ bq,
                                                  const float* __restrict__ bk,
                                                  const float* __restrict__ bv,
                                                  u16* __restrict__ oq,
                                                  u16* __restrict__ ok,
                                                  u16* __restrict__ ov,
                                                  float* __restrict__ of,
                                                  float qscale) {
  constexpr int NT = D_ / 64;  // 12
  __shared__ __align__(16) u16 lA[2][128 * 64];
  __shared__ __align__(16) u16 lB[2][128 * 64];
  const int tid = threadIdx.x, w = tid >> 6, lane = tid & 63;
  const int g = lane >> 4, c = lane & 15;
  const int m0 = blockIdx.x * 128, n0 = blockIdx.y * 128;
  const int wr = w >> 1, wc = w & 1;
  const int srow = lane >> 3, scb = ((lane & 7) * 16) ^ (srow << 4);
  const int sw = (c & 7) << 4;
  const char* Ab = (const char*)A + (size_t)m0 * (D_ * 2);
  const char* Bb = (const char*)Wt + (size_t)n0 * (D_ * 2);

  auto stage = [&](int buf, int t) {
    int k0b = t * 128;
#pragma unroll
    for (int a = 0; a < 4; ++a) {
      int rr = w * 32 + a * 8;
      gload16(Ab + (size_t)(rr + srow) * (D_ * 2) + k0b + scb, &lA[buf][rr * 64]);
      gload16(Bb + (size_t)(rr + srow) * (D_ * 2) + k0b + scb, &lB[buf][rr * 64]);
    }
  };

  f32x4 acc[4][4] = {};
  auto compute = [&](int buf) {
    const char* pa = (const char*)&lA[buf][0];
    const char* pb = (const char*)&lB[buf][0];
#pragma unroll
    for (int kk = 0; kk < 2; ++kk) {
      const int cs = (kk * 64 + g * 16) ^ sw;
      bf16x8 af[4], bf[4];
#pragma unroll
      for (int i = 0; i < 4; ++i)
        af[i] = *(const bf16x8*)(pa + (wr * 64 + i * 16 + c) * 128 + cs);
#pragma unroll
      for (int j = 0; j < 4; ++j)
        bf[j] = *(const bf16x8*)(pb + (wc * 64 + j * 16 + c) * 128 + cs);
      __builtin_amdgcn_s_setprio(1);
#pragma unroll
      for (int i = 0; i < 4; ++i)
#pragma unroll
        for (int j = 0; j < 4; ++j) acc[i][j] = MFMA16(af[i], bf[j], acc[i][j]);
      __builtin_amdgcn_s_setprio(0);
    }
  };

  stage(0, 0);
  int buf = 0;
#pragma unroll 1
  for (int t = 0; t < NT; ++t) {
    if (t + 1 < NT) { stage(buf ^ 1, t + 1); WAITV8(); }
    else            { WAITV0(); }
    BARRIER(); SCHED0();
    compute(buf);
    SCHED0(); WAITL0(); BARRIER();
    buf ^= 1;
  }

  if (MODE == 0) {
    const int p = n0 / D_;  // tile never crosses a projection (768 % 128 == 0)
    const int nn0 = n0 - p * D_;
    const float* bias = p == 0 ? bq : p == 1 ? bk : bv;
    const float sc = p == 0 ? qscale : 1.0f;
#pragma unroll
    for (int j = 0; j < 4; ++j) {
      int nn = nn0 + wc * 64 + j * 16 + c;
      float bvv = bias[nn];
      int h = nn >> 6, d = nn & 63;
#pragma unroll
      for (int i = 0; i < 4; ++i) {
        int m = m0 + wr * 64 + i * 16 + g * 4;
        int b = m >> 11, s = m & (S_ - 1);
        if (p < 2) {
          u16* dst = (p == 0 ? oq : ok) + ((size_t)(b * H_ + h) * S_ + s) * DH + d;
#pragma unroll
          for (int r = 0; r < 4; ++r) dst[(size_t)r * DH] = f2bf((acc[i][j][r] + bvv) * sc);
        } else {
          // sigma: within each 32-key chunk, slots 8q+0..3 <- keys 4q..,
          // slots 8q+4..7 <- keys 16+4q..
          int chunk = s >> 5, kq = (s >> 2) & 7;
          int sb = kq < 4 ? 8 * kq : 8 * (kq - 4) + 4;
          uint2 pk;
          pk.x = pack2r(acc[i][j][0] + bvv, acc[i][j][1] + bvv);
          pk.y = pack2r(acc[i][j][2] + bvv, acc[i][j][3] + bvv);
          *(uint2*)(ov + ((size_t)((b * H_ + h) * DH + d)) * S_ + chunk * 32 + sb) = pk;
        }
      }
    }
  } else {
#pragma unroll
    for (int j = 0; j < 4; ++j) {
      int n = n0 + wc * 64 + j * 16 + c;
      float bvv = bq[n];
#pragma unroll
      for (int i = 0; i < 4; ++i) {
        int m = m0 + wr * 64 + i * 16 + g * 4;
#pragma unroll
        for (int r = 0; r < 4; ++r) of[(size_t)(m + r) * D_ + n] = acc[i][j][r] + bvv;
      }
    }
  }
}

// ---------------- dual-softmax flash attention (round-7 structure) ---------
// grid 768 (1D, XCD-chunk-swizzled), block 256 = 4 waves in a 2x2 grid:
// wave w -> q-half qh=w&1 (32 q, dual Q-frags), key-half kh=w>>1 (32 keys).
// K[64x64]+Vt[64x64] LDS tiles (XOR-swizzled, double-buffered), proven
// stage->compute->syncthreads loop. Mask words STAGED IN LDS (one gload16
// per wave covers the whole batch; direct-global variant cost +5us, r13).
// P-pack via v_cvt_pk_bf16_f32 (1 VALU op vs 3; T12 recipe).
// launch_bounds(256,3): VGPR 84, no spill. NEVER raise the min-waves arg:
// (256,4)->64-VGPR quantum->full spill (r12); (256,5) same (r10).
// Single-pass end reduce overlays staging LDS (disjoint 20KB per q-half).
// Q pre-scaled by log2(e)/8 -> exp2 scores.
__global__ __launch_bounds__(256, 3) void attn(const u16* __restrict__ Q,
                                               const u16* __restrict__ K,
                                               const u16* __restrict__ Vt,
                                               const float* __restrict__ fm,
                                               const u32* __restrict__ mw,
                                               u16* __restrict__ ctx) {
  constexpr int NT = S_ / 64;
  // [0,16K) K dbuf, [16K,32K) V dbuf, [32K,36K) mask words; reduce overlays
  // [0,40K) as two disjoint 20KB regions (one per q-half).
  __shared__ __align__(16) char smem[40960];
  char* lKb = smem;            // 2 x 8192
  char* lVb = smem + 16384;    // 2 x 8192
  char* lMb = smem + 32768;    // 4096

  const int tid = threadIdx.x;
  const int w = tid >> 6, lane = tid & 63;
  const int g = lane >> 4, c = lane & 15;
  const int qh = w & 1, kh = w >> 1;
  const int bid = blockIdx.x;
  const int wg = (bid & 7) * 96 + (bid >> 3);  // bijective XCD-chunk swizzle
  const int qt = wg & 31, bh = wg >> 5;
  const int b = bh / H_, h = bh % H_;
  const int qbase = qt * 64 + qh * 32;

  const u16* Qp = Q + ((size_t)bh * S_ + qbase) * DH;
  const char* Kp = (const char*)(K + (size_t)bh * S_ * DH);
  const char* Vp = (const char*)(Vt + (size_t)bh * DH * S_);
  const float* fmp = fm + b * S_;
  const char* mwp = (const char*)(mw + b * (S_ / 2));

  bf16x8 qf[2][2];
#pragma unroll
  for (int qs = 0; qs < 2; ++qs)
#pragma unroll
    for (int kk = 0; kk < 2; ++kk)
      qf[qs][kk] = *(const bf16x8*)(Qp + (qs * 16 + c) * DH + kk * 32 + g * 8);

  u32 ow = (c == 0) ? 0x3F803F80u : 0u;
  uint4 owv = {ow, ow, ow, ow};
  bf16x8 onesf = __builtin_bit_cast(bf16x8, owv);

  const int srow = lane >> 3;
  const int scb = ((lane & 7) * 16) ^ (srow << 4);
  const int sw = (c & 7) << 4;
  const int r8a = w * 2, r8b = w * 2 + 1;
  const int rowA = r8a * 8 + srow, rowB = r8b * 8 + srow;

  f32x4 accf[2][4] = {}, accb[2][4] = {}, alf[2] = {}, alb[2] = {};

  auto stage = [&](int buf, int t) {
    const char* kb_ = Kp + (size_t)t * 8192;
    const char* vb_ = Vp + (size_t)t * 128;
    gload16(kb_ + (size_t)rowA * 128 + scb, lKb + buf * 8192 + r8a * 1024);
    gload16(kb_ + (size_t)rowB * 128 + scb, lKb + buf * 8192 + r8b * 1024);
    gload16(vb_ + (size_t)rowA * 4096 + scb, lVb + buf * 8192 + r8a * 1024);
    gload16(vb_ + (size_t)rowB * 4096 + scb, lVb + buf * 8192 + r8b * 1024);
  };

  auto compute = [&](int buf, int t) {
    const char* kt = lKb + buf * 8192;
    const char* vtl = lVb + buf * 8192;
    const int kc = kh;  // this wave's key-half
    uint2 m01 = *(const uint2*)(lMb + t * 128 + kc * 64 + g * 8);
    uint2 m23 = *(const uint2*)(lMb + t * 128 + kc * 64 + 32 + g * 8);
    bf16x8 k00 = *(const bf16x8*)(kt + (kc * 32 + c) * 128 + ((g * 16) ^ sw));
    bf16x8 k01 = *(const bf16x8*)(kt + (kc * 32 + c) * 128 + ((64 + g * 16) ^ sw));
    bf16x8 k10 = *(const bf16x8*)(kt + (kc * 32 + 16 + c) * 128 + ((g * 16) ^ sw));
    bf16x8 k11 = *(const bf16x8*)(kt + (kc * 32 + 16 + c) * 128 + ((64 + g * 16) ^ sw));
    const int csel = (kc * 64 + g * 16) ^ sw;
    bf16x8 vf0 = *(const bf16x8*)(vtl + (0 * 16 + c) * 128 + csel);
    bf16x8 vf1 = *(const bf16x8*)(vtl + (1 * 16 + c) * 128 + csel);
    bf16x8 vf2 = *(const bf16x8*)(vtl + (2 * 16 + c) * 128 + csel);
    bf16x8 vf3 = *(const bf16x8*)(vtl + (3 * 16 + c) * 128 + csel);
#pragma unroll
    for (int qs = 0; qs < 2; ++qs) {
      f32x4 st0 = {}, st1 = {};
      __builtin_amdgcn_s_setprio(1);
      st0 = MFMA16(k00, qf[qs][0], st0);
      st0 = MFMA16(k01, qf[qs][1], st0);
      st1 = MFMA16(k10, qf[qs][0], st1);
      st1 = MFMA16(k11, qf[qs][1], st1);
      __builtin_amdgcn_s_setprio(0);
      u32 ew0 = cvtpk(__builtin_amdgcn_exp2f(st0[0]), __builtin_amdgcn_exp2f(st0[1]));
      u32 ew1 = cvtpk(__builtin_amdgcn_exp2f(st0[2]), __builtin_amdgcn_exp2f(st0[3]));
      u32 ew2 = cvtpk(__builtin_amdgcn_exp2f(st1[0]), __builtin_amdgcn_exp2f(st1[1]));
      u32 ew3 = cvtpk(__builtin_amdgcn_exp2f(st1[2]), __builtin_amdgcn_exp2f(st1[3]));
      u32 pf0 = ew0 & m01.x, pf1 = ew1 & m01.y;
      u32 pf2 = ew2 & m23.x, pf3 = ew3 & m23.y;
      uint4 pfv = {pf0, pf1, pf2, pf3};
      uint4 pbv = {ew0 ^ pf0, ew1 ^ pf1, ew2 ^ pf2, ew3 ^ pf3};
      bf16x8 paf = __builtin_bit_cast(bf16x8, pfv);
      bf16x8 pab = __builtin_bit_cast(bf16x8, pbv);
      __builtin_amdgcn_s_setprio(1);
      accf[qs][0] = MFMA16(paf, vf0, accf[qs][0]);
      accb[qs][0] = MFMA16(pab, vf0, accb[qs][0]);
      accf[qs][1] = MFMA16(paf, vf1, accf[qs][1]);
      accb[qs][1] = MFMA16(pab, vf1, accb[qs][1]);
      accf[qs][2] = MFMA16(paf, vf2, accf[qs][2]);
      accb[qs][2] = MFMA16(pab, vf2, accb[qs][2]);
      accf[qs][3] = MFMA16(paf, vf3, accf[qs][3]);
      accb[qs][3] = MFMA16(pab, vf3, accb[qs][3]);
      alf[qs] = MFMA16(paf, onesf, alf[qs]);
      alb[qs] = MFMA16(pab, onesf, alb[qs]);
      __builtin_amdgcn_s_setprio(0);
    }
  };

  // prologue: mask words (1 gload16/wave = 4 KB total) + tile 0, one drain
  gload16(mwp + w * 1024 + lane * 16, lMb + w * 1024);
  stage(0, 0);
  __syncthreads();

  int buf = 0;
#pragma unroll 1
  for (int t = 0; t < NT; ++t) {
    if (t + 1 < NT) stage(buf ^ 1, t + 1);
    compute(buf, t);
    __syncthreads();
    buf ^= 1;
  }

  // ---- single-pass cross-wave key-half reduction (sums are additive) ----
  // region per q-half: 20 f32x4-slots x 64 lanes = 20480 B; overlays staging.
  f32x4* red = (f32x4*)smem + (size_t)qh * 1280;
  if (kh == 1) {
#pragma unroll
    for (int qs = 0; qs < 2; ++qs)
#pragma unroll
      for (int n = 0; n < 4; ++n) {
        red[(qs * 4 + n) * 64 + lane] = accf[qs][n];
        red[(8 + qs * 4 + n) * 64 + lane] = accb[qs][n];
      }
    red[16 * 64 + lane] = alf[0];
    red[17 * 64 + lane] = alf[1];
    red[18 * 64 + lane] = alb[0];
    red[19 * 64 + lane] = alb[1];
  }
  __syncthreads();
  if (kh == 0) {
#pragma unroll
    for (int qs = 0; qs < 2; ++qs)
#pragma unroll
      for (int n = 0; n < 4; ++n) {
        accf[qs][n] += red[(qs * 4 + n) * 64 + lane];
        accb[qs][n] += red[(8 + qs * 4 + n) * 64 + lane];
      }
    alf[0] += red[16 * 64 + lane];
    alf[1] += red[17 * 64 + lane];
    alb[0] += red[18 * 64 + lane];
    alb[1] += red[19 * 64 + lane];

#pragma unroll
    for (int qs = 0; qs < 2; ++qs) {
      const int qw = qbase + qs * 16;
#pragma unroll
      for (int r = 0; r < 4; ++r) {
        int ql = g * 4 + r;
        float lfr = __shfl(alf[qs][r], g * 16);  // D[row=4g+r][col=0] in lane 16g
        float lbr = __shfl(alb[qs][r], g * 16);
        bool fg = fmp[qw + ql] > 0.5f;
        float inv_f = (lfr > 0.f) ? 1.f / lfr : 0.f;
        float inv_b = (lbr > 0.f) ? 1.f / lbr : 0.f;
        float inv_all = 1.f / (lfr + lbr);
#pragma unroll
        for (int n = 0; n < 4; ++n) {
          float o = fg ? (accf[qs][n][r] * inv_f + accb[qs][n][r] * inv_b)
                       : ((accf[qs][n][r] + accb[qs][n][r]) * inv_all);
          ctx[((size_t)(b * S_ + qw + ql)) * D_ + h * DH + n * 16 + c] = f2bf(o);
        }
      }
    }
  }
}

// ---------------- launch ---------------------------------------------------
extern "C" void kernel_launch(void* const* d_in, const int* in_sizes, int n_in,
                              void* d_out, int out_size, void* d_ws, size_t ws_size,
                              hipStream_t stream) {
  const float* hs = (const float*)d_in[0];
  const float* Wq = (const float*)d_in[1];
  const float* bq = (const float*)d_in[2];
  const float* Wk = (const float*)d_in[3];
  const float* bk = (const float*)d_in[4];
  const float* Wv = (const float*)d_in[5];
  const float* bv = (const float*)d_in[6];
  const float* Wo = (const float*)d_in[7];
  const float* bo = (const float*)d_in[8];
  const void* mraw = d_in[9];

  char* ws = (char*)d_ws;
  size_t off = 0;
  auto alloc = [&](size_t bytes) {
    void* p = ws + off;
    off += (bytes + 255) & ~(size_t)255;
    return p;
  };
  u16* hsb = (u16*)alloc((size_t)M_ * D_ * 2);
  u16* wqkvT = (u16*)alloc((size_t)3 * D_ * D_ * 2);
  u16* woT = (u16*)alloc((size_t)D_ * D_ * 2);
  u16* qb = (u16*)alloc((size_t)M_ * D_ * 2);
  u16* kb = (u16*)alloc((size_t)M_ * D_ * 2);
  u16* vtb = (u16*)alloc((size_t)M_ * D_ * 2);
  u16* ctx = (u16*)alloc((size_t)M_ * D_ * 2);
  float* fmf = (float*)alloc((size_t)B_ * S_ * 4);
  u32* mwb = (u32*)alloc((size_t)B_ * S_ / 2 * 4);

  prep<<<PREP_NB_CONV + PREP_NB_W + PREP_NB_MASK, 256, 0, stream>>>(
      hs, Wq, Wk, Wv, Wo, hsb, wqkvT, woT, mraw, fmf, mwb);

  const float qscale = 0.125f * 1.44269504088896f;  // 1/sqrt(Dh) * log2(e)
  gemm128<0><<<dim3(M_ / 128, 3 * D_ / 128), 256, 0, stream>>>(
      hsb, wqkvT, bq, bk, bv, qb, kb, vtb, nullptr, qscale);

  attn<<<dim3(768), 256, 0, stream>>>(qb, kb, vtb, fmf, mwb, ctx);

  gemm128<1><<<dim3(M_ / 128, D_ / 128), 256, 0, stream>>>(
      ctx, woT, bo, nullptr, nullptr, nullptr, nullptr, nullptr, (float*)d_out, 1.0f);
}